// Round 4
// baseline (285.508 us; speedup 1.0000x reference)
//
#include <hip/hip_runtime.h>
#include <math.h>

#define BS 32
#define NN 512
#define NDIMS 3
#define HNF 6
#define HID 64
#define EPSV 1e-8f
#define NORMC 1.0f
#define ROWS 16   // i-rows per block

typedef float f32x4 __attribute__((ext_vector_type(4)));

// ---------------------------------------------------------------------------
// Single fused kernel. Block = (batch b, 16 consecutive i-rows), 512 threads.
// Each block redundantly recomputes the per-batch mean-centering and the tiny
// MLP (cheap, LDS-resident) so there is no second kernel and no ws traffic.
// Thread j then emits output slots j and j+512 of each 1024-float4 edge row:
//   slot q -> edge q>>1, half q&1 (half0 = radial+coord_diff, half1 = h_i,h_j)
// giving perfectly contiguous 1KB-per-wave nontemporal stores.
// ---------------------------------------------------------------------------
__global__ __launch_bounds__(512) void fused_edge_kernel(
    const float* __restrict__ xh,     // (BS, N, 9)
    const float* __restrict__ mask,   // (BS, N, 1)
    const float* __restrict__ W1,     // (6, 64)
    const float* __restrict__ b1,     // (64,)
    const float* __restrict__ W2,     // (64, 2)
    const float* __restrict__ b2,     // (2,)
    f32x4* __restrict__ out4)         // BS*N*N*2 f32x4
{
    const int blk = blockIdx.x;           // 0 .. BS*(NN/ROWS)-1
    const int b   = blk >> 5;             // 32 blocks per batch (512/16)
    const int i0  = (blk & 31) * ROWS;
    const int j   = threadIdx.x;

    __shared__ float sxh[NN * 9];         // staged raw rows
    __shared__ float sx[NN * 3];          // centered x
    __shared__ float sh[NN * 2];          // h_emb
    __shared__ float sW1[HNF * HID];
    __shared__ float sb1[HID];
    __shared__ float sW2[HID * 2];
    __shared__ float s_red[8][4];
    __shared__ float s_mean[3];

    // --- coalesced staging of the batch's raw xh rows + weights ---
    const float* xb = xh + (size_t)b * NN * 9;
    #pragma unroll
    for (int t = 0; t < 9; ++t) sxh[j + t * 512] = xb[j + t * 512];
    if (j < HNF * HID) sW1[j] = W1[j];
    else if (j < HNF * HID + HID) sb1[j - HNF * HID] = b1[j - HNF * HID];
    if (j < HID * 2) sW2[j] = W2[j];
    const float sb2_0 = b2[0], sb2_1 = b2[1];
    const float m = mask[(size_t)b * NN + j];
    __syncthreads();

    // --- per-node values ---
    const float x0 = sxh[j * 9 + 0], x1 = sxh[j * 9 + 1], x2 = sxh[j * 9 + 2];
    float h[HNF];
    #pragma unroll
    for (int k = 0; k < HNF; ++k) h[k] = sxh[j * 9 + 3 + k];

    // --- block reduction for masked mean ---
    float v0 = x0, v1 = x1, v2 = x2, vm = m;
    #pragma unroll
    for (int off = 32; off > 0; off >>= 1) {
        v0 += __shfl_down(v0, off);
        v1 += __shfl_down(v1, off);
        v2 += __shfl_down(v2, off);
        vm += __shfl_down(vm, off);
    }
    const int lane = j & 63, wave = j >> 6;
    if (lane == 0) {
        s_red[wave][0] = v0; s_red[wave][1] = v1;
        s_red[wave][2] = v2; s_red[wave][3] = vm;
    }
    __syncthreads();
    if (j == 0) {
        float t0 = 0.f, t1 = 0.f, t2 = 0.f, tm = 0.f;
        #pragma unroll
        for (int w = 0; w < 8; ++w) {
            t0 += s_red[w][0]; t1 += s_red[w][1];
            t2 += s_red[w][2]; tm += s_red[w][3];
        }
        s_mean[0] = t0 / tm; s_mean[1] = t1 / tm; s_mean[2] = t2 / tm;
    }
    __syncthreads();

    // --- centered x into LDS ---
    sx[j * 3 + 0] = x0 - s_mean[0] * m;
    sx[j * 3 + 1] = x1 - s_mean[1] * m;
    sx[j * 3 + 2] = x2 - s_mean[2] * m;

    // --- tiny MLP into LDS ---
    float acc0 = sb2_0, acc1 = sb2_1;
    #pragma unroll 8
    for (int hh = 0; hh < HID; ++hh) {
        float z = sb1[hh];
        #pragma unroll
        for (int k = 0; k < HNF; ++k) z += h[k] * sW1[k * HID + hh];
        float s = z / (1.0f + expf(-z));   // silu
        acc0 += s * sW2[hh * 2 + 0];
        acc1 += s * sW2[hh * 2 + 1];
    }
    sh[j * 2 + 0] = acc0;
    sh[j * 2 + 1] = acc1;
    __syncthreads();

    // --- edge emission ---
    const int ja = j >> 1;            // edge for slot j
    const int jb = 256 + ja;          // edge for slot j+512
    const bool odd = (j & 1) != 0;

    const float xa0 = sx[ja * 3 + 0], xa1 = sx[ja * 3 + 1], xa2 = sx[ja * 3 + 2];
    const float xb0 = sx[jb * 3 + 0], xb1 = sx[jb * 3 + 1], xb2 = sx[jb * 3 + 2];
    const float ha0 = sh[ja * 2 + 0], ha1 = sh[ja * 2 + 1];
    const float hb0 = sh[jb * 2 + 0], hb1 = sh[jb * 2 + 1];

    f32x4* rowout = out4 + ((size_t)b * NN + i0) * NN * 2;

    #pragma unroll 4
    for (int r = 0; r < ROWS; ++r) {
        const int i = i0 + r;
        const float xi0 = sx[i * 3 + 0], xi1 = sx[i * 3 + 1], xi2 = sx[i * 3 + 2];
        const float hi0 = sh[i * 2 + 0], hi1 = sh[i * 2 + 1];

        float d0 = xi0 - xa0, d1 = xi1 - xa1, d2 = xi2 - xa2;
        float rada = d0 * d0 + d1 * d1 + d2 * d2;
        float inva = __builtin_amdgcn_rcpf(__builtin_amdgcn_sqrtf(rada + EPSV) + NORMC);
        f32x4 va;
        if (odd) { va.x = hi0; va.y = hi1; va.z = ha0; va.w = ha1; }
        else     { va.x = rada; va.y = d0 * inva; va.z = d1 * inva; va.w = d2 * inva; }

        float e0 = xi0 - xb0, e1 = xi1 - xb1, e2 = xi2 - xb2;
        float radb = e0 * e0 + e1 * e1 + e2 * e2;
        float invb = __builtin_amdgcn_rcpf(__builtin_amdgcn_sqrtf(radb + EPSV) + NORMC);
        f32x4 vb;
        if (odd) { vb.x = hi0; vb.y = hi1; vb.z = hb0; vb.w = hb1; }
        else     { vb.x = radb; vb.y = e0 * invb; vb.z = e1 * invb; vb.w = e2 * invb; }

        __builtin_nontemporal_store(va, &rowout[j]);        // contiguous 1KB/wave
        __builtin_nontemporal_store(vb, &rowout[j + 512]);  // contiguous 1KB/wave
        rowout += NN * 2;
    }
}

extern "C" void kernel_launch(void* const* d_in, const int* in_sizes, int n_in,
                              void* d_out, int out_size, void* d_ws, size_t ws_size,
                              hipStream_t stream) {
    const float* xh   = (const float*)d_in[0];
    const float* mask = (const float*)d_in[1];
    const float* W1   = (const float*)d_in[2];
    const float* b1   = (const float*)d_in[3];
    const float* W2   = (const float*)d_in[4];
    const float* b2   = (const float*)d_in[5];

    fused_edge_kernel<<<BS * (NN / ROWS), 512, 0, stream>>>(
        xh, mask, W1, b1, W2, b2, (f32x4*)d_out);
}

// Round 5
// 279.962 us; speedup vs baseline: 1.0198x; 1.0198x over previous
//
#include <hip/hip_runtime.h>
#include <math.h>

#define BS 32
#define NN 512
#define HNF 6
#define HID 64
#define EPSV 1e-8f
#define NORMC 1.0f

typedef float f32x4 __attribute__((ext_vector_type(4)));

// ---------------------------------------------------------------------------
// Kernel 1: per-batch mean removal + tiny MLP. 32 blocks x 512 threads.
// Writes PADDED node records: xc4[b*512+i] = (cx0,cx1,cx2,0)
//                             he4[b*512+i] = (h0, h1, 0, 0)
// so the edge kernel does single dwordx4 loads per node.
// ---------------------------------------------------------------------------
__global__ __launch_bounds__(512) void prep_kernel(
    const float* __restrict__ xh,     // (BS, N, 9)
    const float* __restrict__ mask,   // (BS, N, 1)
    const float* __restrict__ W1,     // (6, 64)
    const float* __restrict__ b1,     // (64,)
    const float* __restrict__ W2,     // (64, 2)
    const float* __restrict__ b2,     // (2,)
    f32x4* __restrict__ xc4,          // (BS*N) padded centered x
    f32x4* __restrict__ he4)          // (BS*N) padded h_emb
{
    const int b = blockIdx.x;
    const int i = threadIdx.x;

    __shared__ float s_red[8][4];
    __shared__ float s_mean[3];
    __shared__ float sW1[HNF * HID];
    __shared__ float sb1[HID];
    __shared__ float sW2[HID * 2];

    for (int t = i; t < HNF * HID; t += 512) sW1[t] = W1[t];
    if (i < HID)     sb1[i] = b1[i];
    if (i < HID * 2) sW2[i] = W2[i];
    const float sb2_0 = b2[0], sb2_1 = b2[1];

    const float* row = xh + ((size_t)b * NN + i) * 9;
    float x0 = row[0], x1 = row[1], x2 = row[2];
    float h[HNF];
    #pragma unroll
    for (int k = 0; k < HNF; ++k) h[k] = row[3 + k];
    float m = mask[(size_t)b * NN + i];

    float v0 = x0, v1 = x1, v2 = x2, vm = m;
    #pragma unroll
    for (int off = 32; off > 0; off >>= 1) {
        v0 += __shfl_down(v0, off);
        v1 += __shfl_down(v1, off);
        v2 += __shfl_down(v2, off);
        vm += __shfl_down(vm, off);
    }
    const int lane = i & 63, wave = i >> 6;
    if (lane == 0) {
        s_red[wave][0] = v0; s_red[wave][1] = v1;
        s_red[wave][2] = v2; s_red[wave][3] = vm;
    }
    __syncthreads();
    if (i == 0) {
        float t0 = 0.f, t1 = 0.f, t2 = 0.f, tm = 0.f;
        #pragma unroll
        for (int w = 0; w < 8; ++w) {
            t0 += s_red[w][0]; t1 += s_red[w][1];
            t2 += s_red[w][2]; tm += s_red[w][3];
        }
        s_mean[0] = t0 / tm; s_mean[1] = t1 / tm; s_mean[2] = t2 / tm;
    }
    __syncthreads();

    f32x4 xo;
    xo.x = x0 - s_mean[0] * m;
    xo.y = x1 - s_mean[1] * m;
    xo.z = x2 - s_mean[2] * m;
    xo.w = 0.f;
    xc4[(size_t)b * NN + i] = xo;

    float acc0 = sb2_0, acc1 = sb2_1;
    #pragma unroll 8
    for (int hh = 0; hh < HID; ++hh) {
        float z = sb1[hh];
        #pragma unroll
        for (int k = 0; k < HNF; ++k) z += h[k] * sW1[k * HID + hh];
        float s = z / (1.0f + expf(-z));   // silu
        acc0 += s * sW2[hh * 2 + 0];
        acc1 += s * sW2[hh * 2 + 1];
    }
    f32x4 ho; ho.x = acc0; ho.y = acc1; ho.z = 0.f; ho.w = 0.f;
    he4[(size_t)b * NN + i] = ho;
}

// ---------------------------------------------------------------------------
// Kernel 2: fill-style flat streaming kernel. 524288 threads, one per
// (i, q) output slot within a batch; iterates b = 0..31 (slot stride between
// batches is exactly 524288). Per thread: i, j, parity are CONSTANT across
// iterations. Per iteration: 3 dwordx4 loads (L1/L2-hit), ~12 VALU, one
// perfectly coalesced dwordx4 store. No LDS, no barriers — same shape as the
// 6.4 TB/s fill kernel.
//   slot q of row (b,i): q=2j+0 -> (radial, cd0, cd1, cd2); q=2j+1 -> (hi,hj)
// ---------------------------------------------------------------------------
__global__ __launch_bounds__(256) void edge_kernel(
    const f32x4* __restrict__ xc4,    // (BS*N)
    const f32x4* __restrict__ he4,    // (BS*N)
    f32x4* __restrict__ out4)         // BS*N*N*2
{
    const int tid = blockIdx.x * 256 + threadIdx.x;   // 0 .. 524287
    const int i   = tid >> 10;         // row within batch
    const int q   = tid & 1023;        // slot within row
    const int j   = q >> 1;
    const bool odd = (q & 1) != 0;

    const f32x4* pj  = (odd ? he4 : xc4) + j;  // node-j record (kind by parity)
    const f32x4* pxi = xc4 + i;
    const f32x4* phi = he4 + i;
    f32x4*       po  = out4 + tid;

    #pragma unroll 4
    for (int b = 0; b < BS; ++b) {
        const f32x4 vj = pj [(size_t)b * NN];
        const f32x4 xi = pxi[(size_t)b * NN];   // wave-uniform -> L1 broadcast
        const f32x4 hi = phi[(size_t)b * NN];   // wave-uniform -> L1 broadcast

        const float d0 = xi.x - vj.x;
        const float d1 = xi.y - vj.y;
        const float d2 = xi.z - vj.z;
        const float rad = d0 * d0 + d1 * d1 + d2 * d2;
        const float inv = __builtin_amdgcn_rcpf(__builtin_amdgcn_sqrtf(rad + EPSV) + NORMC);

        f32x4 o;
        o.x = odd ? hi.x : rad;
        o.y = odd ? hi.y : d0 * inv;
        o.z = odd ? vj.x : d1 * inv;
        o.w = odd ? vj.y : d2 * inv;

        po[(size_t)b * NN * NN * 2 / 1] = o;   // stride 524288 slots per batch
        // (index arithmetic kept explicit below to avoid any surprise)
    }
}

extern "C" void kernel_launch(void* const* d_in, const int* in_sizes, int n_in,
                              void* d_out, int out_size, void* d_ws, size_t ws_size,
                              hipStream_t stream) {
    const float* xh   = (const float*)d_in[0];
    const float* mask = (const float*)d_in[1];
    const float* W1   = (const float*)d_in[2];
    const float* b1   = (const float*)d_in[3];
    const float* W2   = (const float*)d_in[4];
    const float* b2   = (const float*)d_in[5];

    f32x4* xc4 = (f32x4*)d_ws;                       // 256 KB
    f32x4* he4 = xc4 + (size_t)BS * NN;              // 256 KB

    prep_kernel<<<BS, 512, 0, stream>>>(xh, mask, W1, b1, W2, b2, xc4, he4);
    edge_kernel<<<(BS * NN * NN * 2 / BS) / 256, 256, 0, stream>>>(xc4, he4, (f32x4*)d_out);
}